// Round 2
// baseline (2211.451 us; speedup 1.0000x reference)
//
#include <hip/hip_runtime.h>

#define Bq 8
#define Nq 8192
#define NPOINT 1024
#define NSAMPLE 32
#define DF 64
#define RAD2 0.0625f
#define FPS_T 512
#define FPS_PPT (Nq / FPS_T) /* 16 */

// ---------------------------------------------------------------------------
// Kernel 1: farthest point sampling, one block per batch.
// Bit-exactness notes: contract(off) => d = ((dx*dx)+(dy*dy))+(dz*dz) exactly
// as XLA's fused elementwise+reduce; argmax = first occurrence of max
// (strided ownership + (max v, tie min i) reduction reproduces this).
// Writes new_xyz (gathered centroids) directly.
// ---------------------------------------------------------------------------
__global__ void __launch_bounds__(FPS_T, 1)
fps_kernel(const float* __restrict__ xyz, float* __restrict__ new_xyz)
{
#pragma clang fp contract(off)
    extern __shared__ float lds[];
    float* xs = lds;
    float* ys = lds + Nq;
    float* zs = lds + 2 * Nq;
    __shared__ float swv[FPS_T / 64];
    __shared__ int   swi[FPS_T / 64];
    __shared__ int   s_far;

    const int b = blockIdx.x;
    const int t = threadIdx.x;
    const int lane = t & 63;
    const int wid  = t >> 6;
    const float* xb = xyz + (size_t)b * Nq * 3;

    for (int i = t; i < Nq; i += FPS_T) {
        xs[i] = xb[i * 3 + 0];
        ys[i] = xb[i * 3 + 1];
        zs[i] = xb[i * 3 + 2];
    }
    __syncthreads();

    float dist[FPS_PPT];
#pragma unroll
    for (int j = 0; j < FPS_PPT; ++j) dist[j] = 1e10f;

    int farthest = 0;
    float* ob = new_xyz + (size_t)b * NPOINT * 3;

    for (int it = 0; it < NPOINT; ++it) {
        const float cx = xs[farthest];
        const float cy = ys[farthest];
        const float cz = zs[farthest];
        if (t == 0) {
            ob[it * 3 + 0] = cx;
            ob[it * 3 + 1] = cy;
            ob[it * 3 + 2] = cz;
        }
        float bv = -1.0f;
        int   bi = Nq;
#pragma unroll
        for (int j = 0; j < FPS_PPT; ++j) {
            const int i = t + j * FPS_T;           // ascending per thread
            const float dx = xs[i] - cx;
            const float dy = ys[i] - cy;
            const float dz = zs[i] - cz;
            const float d  = dx * dx + dy * dy + dz * dz;  // no-FMA, L-to-R
            const float nd = fminf(dist[j], d);
            dist[j] = nd;
            if (nd > bv) { bv = nd; bi = i; }      // strict > keeps first max
        }
        // wave butterfly reduce: max value, tie -> min index
#pragma unroll
        for (int off = 32; off > 0; off >>= 1) {
            const float ov = __shfl_xor(bv, off, 64);
            const int   oi = __shfl_xor(bi, off, 64);
            if (ov > bv || (ov == bv && oi < bi)) { bv = ov; bi = oi; }
        }
        if (lane == 0) { swv[wid] = bv; swi[wid] = bi; }
        __syncthreads();
        if (t == 0) {
            float v = swv[0]; int i0 = swi[0];
#pragma unroll
            for (int w = 1; w < FPS_T / 64; ++w) {
                if (swv[w] > v || (swv[w] == v && swi[w] < i0)) {
                    v = swv[w]; i0 = swi[w];
                }
            }
            s_far = i0;
        }
        __syncthreads();
        farthest = s_far;
    }
}

// ---------------------------------------------------------------------------
// Kernel 2: ball query, one wave (64 lanes) per query.
// Reference formula: d = ((-2*dot(q,p)) + |q|^2) + |p|^2 with the K=3 dot as
// an FMA chain (Eigen GEMM lowering); norms are plain mul/add reduces.
// Collect the first NSAMPLE indices in ascending order via ballot prefix.
// ---------------------------------------------------------------------------
__global__ void __launch_bounds__(256, 4)
ballq_kernel(const float* __restrict__ xyz, const float* __restrict__ new_xyz,
             int* __restrict__ ball_idx)
{
#pragma clang fp contract(off)
    __shared__ int sel[4][NSAMPLE];
    const int w    = threadIdx.x >> 6;
    const int lane = threadIdx.x & 63;
    const int wq   = blockIdx.x * 4 + w;      // global query id, < Bq*NPOINT
    const int b    = wq >> 10;                // / NPOINT

    const float qx = new_xyz[wq * 3 + 0];
    const float qy = new_xyz[wq * 3 + 1];
    const float qz = new_xyz[wq * 3 + 2];
    const float ssrc = qx * qx + qy * qy + qz * qz;   // plain chain
    const float* xb = xyz + (size_t)b * Nq * 3;

    int cnt = 0;
    for (int base = 0; base < Nq; base += 64) {
        const int i = base + lane;
        const float px = xb[i * 3 + 0];
        const float py = xb[i * 3 + 1];
        const float pz = xb[i * 3 + 2];
        const float dot  = __builtin_fmaf(pz, qz, __builtin_fmaf(py, qy, px * qx));
        const float sdst = px * px + py * py + pz * pz;           // plain chain
        const float d    = (-2.0f * dot + ssrc) + sdst;
        const bool  in   = (d <= RAD2);
        const unsigned long long m = __ballot(in);
        if (in) {
            const int slot = cnt + (int)__popcll(m & ((1ull << lane) - 1ull));
            if (slot < NSAMPLE) sel[w][slot] = i;
        }
        cnt += (int)__popcll(m);
        if (cnt >= NSAMPLE) break;
    }
    // pad with first index (query point itself guarantees cnt >= 1)
    const int first = sel[w][0];
    if (cnt < NSAMPLE) {
        for (int s = cnt + lane; s < NSAMPLE; s += 64) sel[w][s] = first;
    }
    if (lane < NSAMPLE) ball_idx[(size_t)wq * NSAMPLE + lane] = sel[w][lane];
}

// ---------------------------------------------------------------------------
// Kernel 3: gather + concat -> new_points (B, NPOINT, NSAMPLE, 3+DF).
// One thread per output element; coalesced writes.
// ---------------------------------------------------------------------------
__global__ void __launch_bounds__(256)
fill_kernel(const float* __restrict__ xyz, const float* __restrict__ points,
            const float* __restrict__ new_xyz, const int* __restrict__ ball_idx,
            float* __restrict__ new_points)
{
#pragma clang fp contract(off)
    const int TOT = Bq * NPOINT * NSAMPLE * (3 + DF);
    const int t = blockIdx.x * 256 + threadIdx.x;
    if (t >= TOT) return;
    const int c  = t % (3 + DF);
    const int g  = t / (3 + DF);        // (b*NPOINT+q)*NSAMPLE + s
    const int bq = g >> 5;              // / NSAMPLE
    const int b  = bq >> 10;            // / NPOINT
    const int idx = ball_idx[g];
    float v;
    if (c < 3) {
        v = xyz[((size_t)b * Nq + idx) * 3 + c] - new_xyz[(size_t)bq * 3 + c];
    } else {
        v = points[((size_t)b * Nq + idx) * DF + (c - 3)];
    }
    new_points[t] = v;
}

// ---------------------------------------------------------------------------
extern "C" void kernel_launch(void* const* d_in, const int* in_sizes, int n_in,
                              void* d_out, int out_size, void* d_ws, size_t ws_size,
                              hipStream_t stream)
{
    (void)in_sizes; (void)n_in; (void)out_size; (void)ws_size;
    const float* xyz    = (const float*)d_in[0];
    const float* points = (const float*)d_in[1];
    // d_in[2]=npoint, d_in[3]=radius, d_in[4]=nsample are fixed by setup_inputs
    float* out        = (float*)d_out;
    float* new_xyz    = out;                               // Bq*NPOINT*3
    float* new_points = out + (size_t)Bq * NPOINT * 3;     // rest
    int*   ball_idx   = (int*)d_ws;                        // Bq*NPOINT*NSAMPLE

    hipFuncSetAttribute(reinterpret_cast<const void*>(fps_kernel),
                        hipFuncAttributeMaxDynamicSharedMemorySize,
                        3 * Nq * (int)sizeof(float));

    fps_kernel<<<Bq, FPS_T, 3 * Nq * sizeof(float), stream>>>(xyz, new_xyz);
    ballq_kernel<<<(Bq * NPOINT) / 4, 256, 0, stream>>>(xyz, new_xyz, ball_idx);
    const int TOT = Bq * NPOINT * NSAMPLE * (3 + DF);
    fill_kernel<<<(TOT + 255) / 256, 256, 0, stream>>>(xyz, points, new_xyz,
                                                       ball_idx, new_points);
}